// Round 16
// baseline (150.745 us; speedup 1.0000x reference)
//
#include <hip/hip_runtime.h>

#define SEQ 32768
#define QSCALE 0.08838834764831845f

typedef __attribute__((ext_vector_type(8))) short short8;
typedef __attribute__((ext_vector_type(8))) __bf16 bf16x8;
typedef __attribute__((ext_vector_type(16))) float f32x16;
typedef __attribute__((ext_vector_type(4))) float f32x4;
typedef __attribute__((ext_vector_type(4))) int int4v;
typedef __attribute__((ext_vector_type(2))) int int2v;

// [R][128]-short tile swizzle: XOR short-idx bits 3..6 with row&15 — all 16
// 16B slots used -> 32-lane b128 column reads are 2-way (free)
#define SWZ(r, c) ((((r) << 7) + (c)) ^ (((r) & 15) << 3))

__device__ __forceinline__ int cvtpk(float lo, float hi) {
  int r;
  asm("v_cvt_pk_bf16_f32 %0, %1, %2" : "=v"(r) : "v"(lo), "v"(hi));
  return r;
}

__device__ __forceinline__ short bf16b(float f) {
  unsigned u = __builtin_bit_cast(unsigned, f);
  u += 0x7fffu + ((u >> 16) & 1u);   // RNE
  return (short)(u >> 16);
}

__device__ __forceinline__ f32x16 mfma_ii(int4v a, int4v b, f32x16 c) {
  return __builtin_amdgcn_mfma_f32_32x32x16_bf16(
      __builtin_bit_cast(bf16x8, a), __builtin_bit_cast(bf16x8, b), c, 0, 0, 0);
}

// C-layout (reg r <-> n=(r&3)+8*(r>>2)+4*hi, lane) -> A/B frag (reg j <-> n=hi*8+j)
__device__ __forceinline__ int4v build_frag(float e0, float e1, float e2, float e3,
                                            float e4, float e5, float e6, float e7,
                                            int hi) {
  int t0 = cvtpk(e0, e1), t1 = cvtpk(e2, e3);
  int t2 = cvtpk(e4, e5), t3 = cvtpk(e6, e7);
  const int u0 = __shfl_xor(t2, 32), u1 = __shfl_xor(t3, 32);
  const int u2 = __shfl_xor(t0, 32), u3 = __shfl_xor(t1, 32);
  int4v f;
  f[0] = hi ? u0 : t0;
  f[1] = hi ? u1 : t1;
  f[2] = hi ? t2 : u2;
  f[3] = hi ? t3 : u3;
  return f;
}

// ---------------------------------------------------------------------------
// Prep: W fragment table. Wf[side(q,k,v)][tile4][ks8][lane64] = 16B A/B-frag:
// elem j = W[ks*16+(lane>>5)*8+j][side*128 + tile*32 + (lane&31)]  (bf16)
// ---------------------------------------------------------------------------
__global__ void la_prep(const float* __restrict__ Wqkv, int4v* __restrict__ Wf) {
  const int fid = blockIdx.x * 256 + threadIdx.x;  // 6144 frags
  if (fid >= 6144) return;
  const int side = fid >> 11;
  const int rem = fid & 2047;
  const int tile = rem >> 9;
  const int ks = (rem >> 6) & 7;
  const int lane = rem & 63;
  const int k0 = ks * 16 + ((lane >> 5) << 3);
  const int col = side * 128 + tile * 32 + (lane & 31);
  int4v f;
  #pragma unroll
  for (int a = 0; a < 4; ++a)
    f[a] = cvtpk(Wqkv[(k0 + 2 * a) * 384 + col], Wqkv[(k0 + 2 * a + 1) * 384 + col]);
  Wf[fid] = f;
}

// ---------------------------------------------------------------------------
// Pass 1 (r16): r12 body re-tiled to 512 thr / 32-row chunks for 2 blocks/CU.
// 8 waves: proj (h=wv>>2, c=wv&3); ctx tiles (td=wv>>1, teb=(wv&1)*2 ..+1).
// LDS 37 KB: xs dbuf 16K + ptile[2][128][40] 20K (pad-40: conflict-free
// scatter, <=4-way ctx reads, 16B-aligned rows) + sumbuf 1K.
// Protocol: 2-barrier single-buffer (r6/r13-proven).
// grid 8*strips (strips=64 -> 512 blocks = 2/CU); 512 thr.
// ---------------------------------------------------------------------------
__global__ __launch_bounds__(512, 4)
void la_pass1(const float* __restrict__ x, const int4v* __restrict__ Wf,
              float* __restrict__ partials, int strips, int nch) {
  __shared__ __align__(16) short xs[2][32 * 128];   // 16 KB dbuf
  __shared__ __align__(16) short ptile[2][128 * 40];// 20 KB [side][ch][n pad40]
  __shared__ __align__(16) float sumbuf[2][32][4];  // 1 KB [side][n][tile]

  const int tid = threadIdx.x;
  const int lane = tid & 63;
  const int wv = tid >> 6;          // 0..7
  const int l31 = lane & 31;
  const int hi = lane >> 5;
  const int koff = hi << 3;
  const int h = wv >> 2;            // 0=q side, 1=k side
  const int c = wv & 3;             // proj ch-tile
  const int td = wv >> 1;           // ctx d-tile
  const int teb = (wv & 1) << 1;    // ctx first e-tile
  const int b = blockIdx.x / strips;
  const int strip = blockIdx.x - b * strips;
  const long base = (long)b * SEQ + (long)strip * (nch * 32);

  // W fragments for this wave's 32-ch tile (coalesced one-time table load)
  int4v wf[8];
  #pragma unroll
  for (int ks = 0; ks < 8; ++ks)
    wf[ks] = Wf[((((h << 2) + c) << 3) + ks) * 64 + lane];

  const int lr = tid >> 4;          // 0..31
  const int cf = (tid & 15) << 3;   // float col
  {  // preload chunk 0 -> xs[0]
    const float* xp = x + (base + lr) * 128 + cf;
    f32x4 u0 = *(const f32x4*)xp;
    f32x4 u1 = *(const f32x4*)(xp + 4);
    int4v p;
    p[0] = cvtpk(u0[0], u0[1]); p[1] = cvtpk(u0[2], u0[3]);
    p[2] = cvtpk(u1[0], u1[1]); p[3] = cvtpk(u1[2], u1[3]);
    *(int4v*)&xs[0][SWZ(lr, cf)] = p;
  }
  __syncthreads();

  f32x16 ctx0 = {0.f}, ctx1 = {0.f};
  for (int i = 0; i < nch; ++i) {
    const int cur = i & 1;
    const int inx = (i + 1 < nch) ? i + 1 : i;
    const float* xp = x + (base + inx * 32 + lr) * 128 + cf;
    f32x4 u0 = *(const f32x4*)xp;
    f32x4 u1 = *(const f32x4*)(xp + 4);

    // o2: P^T (ch in regs, n in lanes); exp in place -> values AND sums
    f32x16 acc = {0.f};
    #pragma unroll
    for (int ks = 0; ks < 8; ++ks) {
      const int4v xf = *(const int4v*)&xs[cur][SWZ(l31, (ks << 4) + koff)];
      acc = mfma_ii(wf[ks], xf, acc);
    }
    {
      float sa = 0.f, sb = 0.f;
      #pragma unroll
      for (int r = 0; r < 16; r += 2) {
        acc[r] = __expf(acc[r]);         sa += acc[r];
        acc[r + 1] = __expf(acc[r + 1]); sb += acc[r + 1];
      }
      float s = sa + sb;
      s += __shfl_xor(s, 32);       // lanes n and n+32 hold complementary ch-halves
      if (!hi) sumbuf[h][l31][c] = s;
    }

    {  // stage next chunk (reads of this xs buffer are 2 barriers back)
      int4v p;
      p[0] = cvtpk(u0[0], u0[1]); p[1] = cvtpk(u0[2], u0[3]);
      p[2] = cvtpk(u1[0], u1[1]); p[3] = cvtpk(u1[2], u1[3]);
      *(int4v*)&xs[cur ^ 1][SWZ(lr, cf)] = p;
    }
    __syncthreads();                    // B1: sums + stage visible

    // norm+transpose write: q absorbs QSCALE/(sq*sk); k stores raw exp
    {
      short* pt = &ptile[h][0];
      if (h == 0) {
        const f32x4 sq = *(const f32x4*)&sumbuf[0][l31][0];
        const f32x4 sk = *(const f32x4*)&sumbuf[1][l31][0];
        const float invn = QSCALE * __builtin_amdgcn_rcpf(
            (sq[0] + sq[1] + sq[2] + sq[3]) * (sk[0] + sk[1] + sk[2] + sk[3]));
        #pragma unroll
        for (int r = 0; r < 16; ++r) {
          const int ch = (c << 5) + (r & 3) + ((r >> 2) << 3) + (hi << 2);
          pt[ch * 40 + l31] = bf16b(acc[r] * invn);
        }
      } else {
        #pragma unroll
        for (int r = 0; r < 16; ++r) {
          const int ch = (c << 5) + (r & 3) + ((r >> 2) << 3) + (hi << 2);
          pt[ch * 40 + l31] = bf16b(acc[r]);
        }
      }
    }
    __syncthreads();                    // B2: ptile ready

    // immediate ctx: 2 tiles x 2 ksteps (K = 32 rows)
    #pragma unroll
    for (int ks = 0; ks < 2; ++ks) {
      const int kk = (ks << 4) + koff;
      const int4v aq = *(const int4v*)&ptile[0][((td << 5) + l31) * 40 + kk];
      ctx0 = mfma_ii(aq, *(const int4v*)&ptile[1][((teb << 5) + l31) * 40 + kk], ctx0);
      ctx1 = mfma_ii(aq, *(const int4v*)&ptile[1][(((teb + 1) << 5) + l31) * 40 + kk], ctx1);
    }
  }

  float* pout = partials + (long)blockIdx.x * 16384;
  #pragma unroll
  for (int r = 0; r < 16; ++r) {
    const int drow = (td << 5) + (r & 3) + ((r >> 2) << 3) + (hi << 2);
    pout[(drow << 7) + (teb << 5) + l31] = ctx0[r];
    pout[(drow << 7) + ((teb + 1) << 5) + l31] = ctx1[r];
  }
}

// ---------------------------------------------------------------------------
// Reduce partials -> ctx[b]   (grid 128 = 8 batches x 16 slices)
// ---------------------------------------------------------------------------
__global__ void la_reduce(const float* __restrict__ partials, float* __restrict__ ctx,
                          int strips) {
  const int b = blockIdx.x >> 4;
  const int sl = blockIdx.x & 15;
  const int idx = (sl << 10) + ((int)threadIdx.x << 2);
  f32x4 acc = {0.f};
  for (int st = 0; st < strips; ++st)
    acc += *(const f32x4*)(partials + ((long)(b * strips + st) << 14) + idx);
  *(f32x4*)(ctx + ((long)b << 14) + idx) = acc;
}

// ---------------------------------------------------------------------------
// Mt = (ctx^T W_out)^T stored as interleaved-column MFMA B-frag table:
// Mtf[b][j4][ks8][lane] 16B: elem m = Mt[4*(lane&31)+j][ks*16+(lane>>5)*8+m]
// ---------------------------------------------------------------------------
__global__ void la_mkern(const float* __restrict__ ctx, const float* __restrict__ Wout,
                         int4v* __restrict__ Mtf) {
  __shared__ __align__(16) float cl[128 * 132];
  __shared__ float wo[128 * 32];
  const int tid = threadIdx.x;
  const int b = blockIdx.x >> 2;
  const int d0 = (blockIdx.x & 3) << 5;
  const float* cp = ctx + ((long)b << 14);
  for (int i = tid << 2; i < 16384; i += 1024) {
    f32x4 v = *(const f32x4*)(cp + i);
    *(f32x4*)&cl[(i >> 7) * 132 + (i & 127)] = v;
  }
  for (int i = tid; i < 128 * 32; i += 256)
    wo[i] = Wout[((i >> 5) << 7) + d0 + (i & 31)];
  __syncthreads();
  const int dq = tid >> 3;            // d' within [0,32)
  const int e0 = (tid & 7) << 4;
  float acc[16];
  #pragma unroll
  for (int i = 0; i < 16; ++i) acc[i] = 0.0f;
  for (int d = 0; d < 128; ++d) {
    const float w = wo[(d << 5) + dq];
    const float* cr = &cl[d * 132 + e0];
    #pragma unroll
    for (int i = 0; i < 16; ++i) acc[i] += cr[i] * w;
  }
  const int dp = d0 + dq;             // global d'
  const int j = dp & 3, l = dp >> 2, ks = e0 >> 4;
  int4v lo, hi2;
  lo[0] = cvtpk(acc[0], acc[1]);   lo[1] = cvtpk(acc[2], acc[3]);
  lo[2] = cvtpk(acc[4], acc[5]);   lo[3] = cvtpk(acc[6], acc[7]);
  hi2[0] = cvtpk(acc[8], acc[9]);  hi2[1] = cvtpk(acc[10], acc[11]);
  hi2[2] = cvtpk(acc[12], acc[13]); hi2[3] = cvtpk(acc[14], acc[15]);
  int4v* dst = Mtf + ((((long)b << 2) + j) * 8 + ks) * 64;
  dst[l] = lo;
  dst[32 + l] = hi2;
}

// ---------------------------------------------------------------------------
// Pass 2 (r15-exact): barrier-free, wave-independent; two-burst staging +
// just-in-time vf build; (256,3) no-spill bound.
// ---------------------------------------------------------------------------
__global__ __launch_bounds__(256, 3)
void la_pass2(const float* __restrict__ x, const int4v* __restrict__ Wf,
              const int4v* __restrict__ Mtf, const float* __restrict__ bout,
              float* __restrict__ out) {
  __shared__ __align__(16) short xs[4][32 * 128];   // 8 KB per wave

  const int tid = threadIdx.x;
  const int lane = tid & 63;
  const int wv = tid >> 6;
  const int l31 = lane & 31;
  const int hi = lane >> 5;
  const int koff = hi << 3;
  const int b = blockIdx.x >> 8;
  const int chunk = blockIdx.x & 255;
  const long row0 = (long)b * SEQ + (long)chunk * 128 + (wv << 5);

  {  // two-burst stage: 8 loads -> convert+write, 8 loads -> convert+write
    const float* xb = x + row0 * 128;
    f32x4 uA[8];
    #pragma unroll
    for (int t = 0; t < 8; ++t)
      uA[t] = *(const f32x4*)(xb + t * 256 + lane * 4);
    f32x4 uB[8];
    #pragma unroll
    for (int t = 0; t < 8; ++t)
      uB[t] = *(const f32x4*)(xb + (t + 8) * 256 + lane * 4);
    #pragma unroll
    for (int t = 0; t < 8; ++t) {
      const int flat = t * 256 + lane * 4;
      int2v w;
      w[0] = cvtpk(uA[t][0], uA[t][1]);
      w[1] = cvtpk(uA[t][2], uA[t][3]);
      *(int2v*)&xs[wv][SWZ(flat >> 7, flat & 127)] = w;
    }
    #pragma unroll
    for (int t = 0; t < 8; ++t) {
      const int flat = (t + 8) * 256 + lane * 4;
      int2v w;
      w[0] = cvtpk(uB[t][0], uB[t][1]);
      w[1] = cvtpk(uB[t][2], uB[t][3]);
      *(int2v*)&xs[wv][SWZ(flat >> 7, flat & 127)] = w;
    }
  }
  const f32x4 bias = *(const f32x4*)(bout + (l31 << 2));   // d' = 4*l31+j
  asm volatile("s_waitcnt lgkmcnt(0)" ::: "memory");       // wave-local LDS drain
  __builtin_amdgcn_sched_barrier(0);

  // x fragments for this wave's 32 rows
  int4v xfr[8];
  #pragma unroll
  for (int ks = 0; ks < 8; ++ks)
    xfr[ks] = *(const int4v*)&xs[wv][SWZ(l31, (ks << 4) + koff)];

  // v-proj o2: C[ch in regs][n=l31], 4 ch-tiles; W-frags from L2 table
  const int4v* WvT = Wf + 2 * 2048;   // side 2 (v)
  f32x16 a0 = {0.f}, a1 = {0.f}, a2 = {0.f}, a3 = {0.f};
  #pragma unroll
  for (int ks = 0; ks < 8; ++ks) {
    a0 = mfma_ii(WvT[(0 * 8 + ks) * 64 + lane], xfr[ks], a0);
    a1 = mfma_ii(WvT[(1 * 8 + ks) * 64 + lane], xfr[ks], a1);
    a2 = mfma_ii(WvT[(2 * 8 + ks) * 64 + lane], xfr[ks], a2);
    a3 = mfma_ii(WvT[(3 * 8 + ks) * 64 + lane], xfr[ks], a3);
  }

  // softmax: fully lane-local sum over 128 channels, normalize in f32
  float s = 0.f;
  #pragma unroll
  for (int r = 0; r < 16; ++r) {
    a0[r] = __expf(a0[r]); s += a0[r];
    a1[r] = __expf(a1[r]); s += a1[r];
    a2[r] = __expf(a2[r]); s += a2[r];
    a3[r] = __expf(a3[r]); s += a3[r];
  }
  s += __shfl_xor(s, 32);
  const float inv = __builtin_amdgcn_rcpf(s);
  #pragma unroll
  for (int r = 0; r < 16; ++r) {
    a0[r] *= inv; a1[r] *= inv; a2[r] *= inv; a3[r] *= inv;
  }

  // out[n][d'] = v @ Mt^T + bias ; just-in-time vf per K=16 step
  const int4v* MtB = Mtf + ((long)b << 11);
  f32x16 o0 = {0.f}, o1 = {0.f}, o2 = {0.f}, o3 = {0.f};
#define OUT_T(T, AT)                                                          \
  {                                                                           \
    const int4v f0 = build_frag(AT[0], AT[1], AT[2], AT[3],                   \
                                AT[4], AT[5], AT[6], AT[7], hi);              \
    o0 = mfma_ii(f0, MtB[(0 * 8 + 2 * T) * 64 + lane], o0);                   \
    o1 = mfma_ii(f0, MtB[(1 * 8 + 2 * T) * 64 + lane], o1);                   \
    o2 = mfma_ii(f0, MtB[(2 * 8 + 2 * T) * 64 + lane], o2);                   \
    o3 = mfma_ii(f0, MtB[(3 * 8 + 2 * T) * 64 + lane], o3);                   \
    const int4v f1 = build_frag(AT[8], AT[9], AT[10], AT[11],                 \
                                AT[12], AT[13], AT[14], AT[15], hi);          \
    o0 = mfma_ii(f1, MtB[(0 * 8 + 2 * T + 1) * 64 + lane], o0);               \
    o1 = mfma_ii(f1, MtB[(1 * 8 + 2 * T + 1) * 64 + lane], o1);               \
    o2 = mfma_ii(f1, MtB[(2 * 8 + 2 * T + 1) * 64 + lane], o2);               \
    o3 = mfma_ii(f1, MtB[(3 * 8 + 2 * T + 1) * 64 + lane], o3);               \
  }
  OUT_T(0, a0)
  OUT_T(1, a1)
  OUT_T(2, a2)
  OUT_T(3, a3)
#undef OUT_T

  float* obase = out + row0 * 128 + (l31 << 2);
  #pragma unroll
  for (int r = 0; r < 16; ++r) {
    const int n = (r & 3) + ((r >> 2) << 3) + (hi << 2);
    f32x4 v;
    v[0] = o0[r] + bias[0];
    v[1] = o1[r] + bias[1];
    v[2] = o2[r] + bias[2];
    v[3] = o3[r] + bias[3];
    *(f32x4*)(obase + (long)n * 128) = v;
  }
}

extern "C" void kernel_launch(void* const* d_in, const int* in_sizes, int n_in,
                              void* d_out, int out_size, void* d_ws, size_t ws_size,
                              hipStream_t stream) {
  const float* x = (const float*)d_in[0];
  const float* Wqkv = (const float*)d_in[1];
  const float* Wout = (const float*)d_in[2];
  const float* bout = (const float*)d_in[3];
  float* out = (float*)d_out;

  const size_t fixed = (size_t)8 * 16384 * 4 + (size_t)16384 * 16 + (size_t)6144 * 16;
  const int strips = (ws_size >= (size_t)8 * 64 * 16384 * 4 + fixed) ? 64 : 32;
  const int nch = SEQ / (strips * 32);

  float* partials = (float*)d_ws;                        // 8*strips * 16384 f32
  float* ctx = partials + (size_t)8 * strips * 16384;    // 8 * 16384 f32
  int4v* Mtf = (int4v*)(ctx + 8 * 16384);                // 16384 int4v (256 KB)
  int4v* Wf = Mtf + 16384;                               // 6144 int4v (96 KB)

  la_prep<<<dim3(24), dim3(256), 0, stream>>>(Wqkv, Wf);
  la_pass1<<<dim3(8 * strips), dim3(512), 0, stream>>>(x, Wf, partials, strips, nch);
  la_reduce<<<dim3(128), dim3(256), 0, stream>>>(partials, ctx, strips);
  la_mkern<<<dim3(32), dim3(256), 0, stream>>>(ctx, Wout, Mtf);
  la_pass2<<<dim3(2048), dim3(256), 0, stream>>>(x, Wf, Mtf, bout, out);
}

// Round 17
// 144.007 us; speedup vs baseline: 1.0468x; 1.0468x over previous
//
#include <hip/hip_runtime.h>

#define SEQ 32768
#define QSCALE 0.08838834764831845f
#define NCH 16   // 64-row chunks per strip (strips=32)

typedef __attribute__((ext_vector_type(8))) short short8;
typedef __attribute__((ext_vector_type(8))) __bf16 bf16x8;
typedef __attribute__((ext_vector_type(16))) float f32x16;
typedef __attribute__((ext_vector_type(4))) float f32x4;
typedef __attribute__((ext_vector_type(2))) float f32x2;
typedef __attribute__((ext_vector_type(4))) int int4v;
typedef __attribute__((ext_vector_type(2))) int int2v;

// [R][128]-short tile swizzle: XOR short-idx bits 3..6 with row&15 — all 16
// 16B slots used -> 32-lane b128 column reads are 2-way (free)
#define SWZ(r, c) ((((r) << 7) + (c)) ^ (((r) & 15) << 3))
// [128ch][64n]-short value tile: 8 slots (col space 64 shorts)
#define PSWZ(ch, n) ((((ch) << 6) + (n)) ^ (((ch) & 7) << 3))

__device__ __forceinline__ int cvtpk(float lo, float hi) {
  int r;
  asm("v_cvt_pk_bf16_f32 %0, %1, %2" : "=v"(r) : "v"(lo), "v"(hi));
  return r;
}

__device__ __forceinline__ short bf16b(float f) {
  unsigned u = __builtin_bit_cast(unsigned, f);
  u += 0x7fffu + ((u >> 16) & 1u);   // RNE
  return (short)(u >> 16);
}

__device__ __forceinline__ f32x16 mfma_ii(int4v a, int4v b, f32x16 c) {
  return __builtin_amdgcn_mfma_f32_32x32x16_bf16(
      __builtin_bit_cast(bf16x8, a), __builtin_bit_cast(bf16x8, b), c, 0, 0, 0);
}

// C-layout (reg r <-> n=(r&3)+8*(r>>2)+4*hi, lane) -> A/B frag (reg j <-> n=hi*8+j)
__device__ __forceinline__ int4v build_frag(float e0, float e1, float e2, float e3,
                                            float e4, float e5, float e6, float e7,
                                            int hi) {
  int t0 = cvtpk(e0, e1), t1 = cvtpk(e2, e3);
  int t2 = cvtpk(e4, e5), t3 = cvtpk(e6, e7);
  const int u0 = __shfl_xor(t2, 32), u1 = __shfl_xor(t3, 32);
  const int u2 = __shfl_xor(t0, 32), u3 = __shfl_xor(t1, 32);
  int4v f;
  f[0] = hi ? u0 : t0;
  f[1] = hi ? u1 : t1;
  f[2] = hi ? t2 : u2;
  f[3] = hi ? t3 : u3;
  return f;
}

// ---------------------------------------------------------------------------
// Prep: W fragment table. Wf[side(q,k,v)][tile4][ks8][lane64] = 16B A/B-frag:
// elem j = W[ks*16+(lane>>5)*8+j][side*128 + tile*32 + (lane&31)]  (bf16)
// ---------------------------------------------------------------------------
__global__ void la_prep(const float* __restrict__ Wqkv, int4v* __restrict__ Wf) {
  const int fid = blockIdx.x * 256 + threadIdx.x;  // 6144 frags
  if (fid >= 6144) return;
  const int side = fid >> 11;
  const int rem = fid & 2047;
  const int tile = rem >> 9;
  const int ks = (rem >> 6) & 7;
  const int lane = rem & 63;
  const int k0 = ks * 16 + ((lane >> 5) << 3);
  const int col = side * 128 + tile * 32 + (lane & 31);
  int4v f;
  #pragma unroll
  for (int a = 0; a < 4; ++a)
    f[a] = cvtpk(Wqkv[(k0 + 2 * a) * 384 + col], Wqkv[(k0 + 2 * a + 1) * 384 + col]);
  Wf[fid] = f;
}

// ---------------------------------------------------------------------------
// Pass 1 (r12-exact, proven 149.3 µs): single o2 projection, scatter-transpose
// ptile, 1 barrier/chunk, trailing ctx, 16-slot SWZ, q-absorbs-norm.
// grid 256 = 8 batches x 32 strips; 1024 thr (16 waves).
// ---------------------------------------------------------------------------
__global__ __launch_bounds__(1024, 4)
void la_pass1(const float* __restrict__ x, const int4v* __restrict__ Wf,
              float* __restrict__ partials) {
  __shared__ __align__(16) short xs[2][64 * 128];        // 32 KB dbuf
  __shared__ __align__(16) short ptile[2][2][128 * 64];  // 64 KB [buf][side][ch][n]
  __shared__ __align__(16) float sumbuf[2][2][2][32][4]; // 4 KB [buf][side][rh][n][tile]

  const int tid = threadIdx.x;
  const int lane = tid & 63;
  const int wv = tid >> 6;          // 0..15
  const int l31 = lane & 31;
  const int hi = lane >> 5;
  const int koff = hi << 3;
  const int h = wv >> 3;            // 0=q side, 1=k side
  const int c = (wv >> 1) & 3;      // proj ch-tile
  const int rh = wv & 1;            // row half
  const int td = wv >> 2;           // ctx d-tile
  const int te = wv & 3;            // ctx e-tile
  const int b = blockIdx.x >> 5;
  const int strip = blockIdx.x & 31;
  const long base = (long)b * SEQ + (long)strip * (NCH * 64);

  // W fragments for this wave's 32-ch tile (coalesced one-time table load)
  int4v wf[8];
  #pragma unroll
  for (int ks = 0; ks < 8; ++ks)
    wf[ks] = Wf[((((h << 2) + c) << 3) + ks) * 64 + lane];

  const int lr = tid >> 4;          // 0..63
  const int cf = (tid & 15) << 3;   // float col
  {  // preload chunk 0 -> xs[0]
    const float* xp = x + (base + lr) * 128 + cf;
    f32x4 u0 = *(const f32x4*)xp;
    f32x4 u1 = *(const f32x4*)(xp + 4);
    int4v p;
    p[0] = cvtpk(u0[0], u0[1]); p[1] = cvtpk(u0[2], u0[3]);
    p[2] = cvtpk(u1[0], u1[1]); p[3] = cvtpk(u1[2], u1[3]);
    *(int4v*)&xs[0][SWZ(lr, cf)] = p;
  }
  __syncthreads();

  f32x16 ctx = {0.f};
  const int r0 = rh << 5;           // this wave's first row in the chunk
  for (int i = 0; i < NCH; ++i) {
    const int cur = i & 1;
    const int inx = (i + 1 < NCH) ? i + 1 : i;
    const float* xp = x + (base + inx * 64 + lr) * 128 + cf;
    f32x4 u0 = *(const f32x4*)xp;
    f32x4 u1 = *(const f32x4*)(xp + 4);

    // o2: P^T (ch in regs, n in lanes); exp in place -> values AND sums
    f32x16 acc = {0.f};
    #pragma unroll
    for (int ks = 0; ks < 8; ++ks) {
      const int4v xf = *(const int4v*)&xs[cur][SWZ(r0 + l31, (ks << 4) + koff)];
      acc = mfma_ii(wf[ks], xf, acc);
    }
    {
      float sa = 0.f, sb = 0.f;
      #pragma unroll
      for (int r = 0; r < 16; r += 2) {
        acc[r] = __expf(acc[r]);         sa += acc[r];
        acc[r + 1] = __expf(acc[r + 1]); sb += acc[r + 1];
      }
      float s = sa + sb;
      s += __shfl_xor(s, 32);       // lanes n and n+32 hold complementary ch-halves
      if (!hi) sumbuf[cur][h][rh][l31][c] = s;
    }

    {  // stage next chunk (re-write of read buffer is 1 barrier away)
      int4v p;
      p[0] = cvtpk(u0[0], u0[1]); p[1] = cvtpk(u0[2], u0[3]);
      p[2] = cvtpk(u1[0], u1[1]); p[3] = cvtpk(u1[2], u1[3]);
      *(int4v*)&xs[cur ^ 1][SWZ(lr, cf)] = p;
    }
    __syncthreads();                    // the ONLY barrier per chunk

    // trailing ctx on PREVIOUS chunk's tiles FIRST (fills MFMA pipe early)
    if (i > 0) {
      const int pb = cur ^ 1;
      #pragma unroll
      for (int ks = 0; ks < 4; ++ks) {
        const int4v aq = *(const int4v*)&ptile[pb][0][PSWZ((td << 5) + l31, (ks << 4) + koff)];
        const int4v bk = *(const int4v*)&ptile[pb][1][PSWZ((te << 5) + l31, (ks << 4) + koff)];
        ctx = mfma_ii(aq, bk, ctx);
      }
    }

    // norm+transpose write: q absorbs QSCALE/(sq*sk); k stores raw exp
    {
      short* pt = &ptile[cur][h][0];
      const int n = (rh << 5) + l31;
      if (h == 0) {
        const f32x4 sq = *(const f32x4*)&sumbuf[cur][0][rh][l31][0];
        const f32x4 sk = *(const f32x4*)&sumbuf[cur][1][rh][l31][0];
        const float invn = QSCALE * __builtin_amdgcn_rcpf(
            (sq[0] + sq[1] + sq[2] + sq[3]) * (sk[0] + sk[1] + sk[2] + sk[3]));
        #pragma unroll
        for (int r = 0; r < 16; ++r) {
          const int ch = (c << 5) + (r & 3) + ((r >> 2) << 3) + (hi << 2);
          pt[PSWZ(ch, n)] = bf16b(acc[r] * invn);
        }
      } else {
        #pragma unroll
        for (int r = 0; r < 16; ++r) {
          const int ch = (c << 5) + (r & 3) + ((r >> 2) << 3) + (hi << 2);
          pt[PSWZ(ch, n)] = bf16b(acc[r]);
        }
      }
    }
  }
  __syncthreads();   // final: chunk NCH-1 tile writes visible
  {
    const int pb = (NCH - 1) & 1;
    #pragma unroll
    for (int ks = 0; ks < 4; ++ks) {
      const int4v aq = *(const int4v*)&ptile[pb][0][PSWZ((td << 5) + l31, (ks << 4) + koff)];
      const int4v bk = *(const int4v*)&ptile[pb][1][PSWZ((te << 5) + l31, (ks << 4) + koff)];
      ctx = mfma_ii(aq, bk, ctx);
    }
  }

  float* pout = partials + (long)blockIdx.x * 16384;
  #pragma unroll
  for (int r = 0; r < 16; ++r) {
    const int drow = (td << 5) + (r & 3) + ((r >> 2) << 3) + (hi << 2);
    pout[(drow << 7) + (te << 5) + l31] = ctx[r];
  }
}

// ---------------------------------------------------------------------------
// Reduce partials -> ctx[b]   (grid 128 = 8 batches x 16 slices)
// ---------------------------------------------------------------------------
__global__ void la_reduce(const float* __restrict__ partials, float* __restrict__ ctx,
                          int strips) {
  const int b = blockIdx.x >> 4;
  const int sl = blockIdx.x & 15;
  const int idx = (sl << 10) + ((int)threadIdx.x << 2);
  f32x4 acc = {0.f};
  for (int st = 0; st < strips; ++st)
    acc += *(const f32x4*)(partials + ((long)(b * strips + st) << 14) + idx);
  *(f32x4*)(ctx + ((long)b << 14) + idx) = acc;
}

// ---------------------------------------------------------------------------
// Mt = (ctx^T W_out)^T stored as PAIR-interleaved MFMA B-frag table:
// Mtf[b][half2][j2][ks8][lane] 16B: elem m = Mt[half*64 + 2*(lane&31) + j]
//                                            [ks*16 + (lane>>5)*8 + m]
// (d' = half*64 + 2*l31 + j so pass2 stores coalesced f32x2 per d'-half)
// ---------------------------------------------------------------------------
__global__ void la_mkern(const float* __restrict__ ctx, const float* __restrict__ Wout,
                         int4v* __restrict__ Mtf) {
  __shared__ __align__(16) float cl[128 * 132];
  __shared__ float wo[128 * 32];
  const int tid = threadIdx.x;
  const int b = blockIdx.x >> 2;
  const int d0 = (blockIdx.x & 3) << 5;
  const float* cp = ctx + ((long)b << 14);
  for (int i = tid << 2; i < 16384; i += 1024) {
    f32x4 v = *(const f32x4*)(cp + i);
    *(f32x4*)&cl[(i >> 7) * 132 + (i & 127)] = v;
  }
  for (int i = tid; i < 128 * 32; i += 256)
    wo[i] = Wout[((i >> 5) << 7) + d0 + (i & 31)];
  __syncthreads();
  const int dq = tid >> 3;            // d' within [0,32)
  const int e0 = (tid & 7) << 4;
  float acc[16];
  #pragma unroll
  for (int i = 0; i < 16; ++i) acc[i] = 0.0f;
  for (int d = 0; d < 128; ++d) {
    const float w = wo[(d << 5) + dq];
    const float* cr = &cl[d * 132 + e0];
    #pragma unroll
    for (int i = 0; i < 16; ++i) acc[i] += cr[i] * w;
  }
  const int dp = d0 + dq;             // global d'
  const int half = dp >> 6, jj = dp & 1, ll = (dp >> 1) & 31, ks = e0 >> 4;
  int4v lo, hi2;
  lo[0] = cvtpk(acc[0], acc[1]);   lo[1] = cvtpk(acc[2], acc[3]);
  lo[2] = cvtpk(acc[4], acc[5]);   lo[3] = cvtpk(acc[6], acc[7]);
  hi2[0] = cvtpk(acc[8], acc[9]);  hi2[1] = cvtpk(acc[10], acc[11]);
  hi2[2] = cvtpk(acc[12], acc[13]); hi2[3] = cvtpk(acc[14], acc[15]);
  int4v* dst = Mtf + (long)b * 2048 + half * 1024 + jj * 512 + ks * 64;
  dst[ll] = lo;
  dst[32 + ll] = hi2;
}

// ---------------------------------------------------------------------------
// Pass 2 (r17): barrier-free, wave-independent; out-GEMM SPLIT into two
// d'-half passes (o-pair liveness 64->32) so the kernel genuinely fits
// __launch_bounds__(256,4): 4 blocks/CU (16 waves) vs 3. Pair-interleaved
// Mtf -> coalesced f32x2 stores per half.
// ---------------------------------------------------------------------------
__global__ __launch_bounds__(256, 4)
void la_pass2(const float* __restrict__ x, const int4v* __restrict__ Wf,
              const int4v* __restrict__ Mtf, const float* __restrict__ bout,
              float* __restrict__ out) {
  __shared__ __align__(16) short xs[4][32 * 128];   // 8 KB per wave

  const int tid = threadIdx.x;
  const int lane = tid & 63;
  const int wv = tid >> 6;
  const int l31 = lane & 31;
  const int hi = lane >> 5;
  const int koff = hi << 3;
  const int b = blockIdx.x >> 8;
  const int chunk = blockIdx.x & 255;
  const long row0 = (long)b * SEQ + (long)chunk * 128 + (wv << 5);

  {  // two-burst stage: 8 loads -> convert+write, 8 loads -> convert+write
    const float* xb = x + row0 * 128;
    f32x4 uA[8];
    #pragma unroll
    for (int t = 0; t < 8; ++t)
      uA[t] = *(const f32x4*)(xb + t * 256 + lane * 4);
    f32x4 uB[8];
    #pragma unroll
    for (int t = 0; t < 8; ++t)
      uB[t] = *(const f32x4*)(xb + (t + 8) * 256 + lane * 4);
    #pragma unroll
    for (int t = 0; t < 8; ++t) {
      const int flat = t * 256 + lane * 4;
      int2v w;
      w[0] = cvtpk(uA[t][0], uA[t][1]);
      w[1] = cvtpk(uA[t][2], uA[t][3]);
      *(int2v*)&xs[wv][SWZ(flat >> 7, flat & 127)] = w;
    }
    #pragma unroll
    for (int t = 0; t < 8; ++t) {
      const int flat = (t + 8) * 256 + lane * 4;
      int2v w;
      w[0] = cvtpk(uB[t][0], uB[t][1]);
      w[1] = cvtpk(uB[t][2], uB[t][3]);
      *(int2v*)&xs[wv][SWZ(flat >> 7, flat & 127)] = w;
    }
  }
  const f32x2 bA = *(const f32x2*)(bout + (l31 << 1));        // d' = 2*l31+j
  const f32x2 bB = *(const f32x2*)(bout + 64 + (l31 << 1));   // d' = 64+2*l31+j
  asm volatile("s_waitcnt lgkmcnt(0)" ::: "memory");          // wave-local LDS drain
  __builtin_amdgcn_sched_barrier(0);

  // x fragments for this wave's 32 rows
  int4v xfr[8];
  #pragma unroll
  for (int ks = 0; ks < 8; ++ks)
    xfr[ks] = *(const int4v*)&xs[wv][SWZ(l31, (ks << 4) + koff)];

  // v-proj o2: C[ch in regs][n=l31], 4 ch-tiles; W-frags from L2 table
  const int4v* WvT = Wf + 2 * 2048;   // side 2 (v)
  f32x16 a0 = {0.f}, a1 = {0.f}, a2 = {0.f}, a3 = {0.f};
  #pragma unroll
  for (int ks = 0; ks < 8; ++ks) {
    a0 = mfma_ii(WvT[(0 * 8 + ks) * 64 + lane], xfr[ks], a0);
    a1 = mfma_ii(WvT[(1 * 8 + ks) * 64 + lane], xfr[ks], a1);
    a2 = mfma_ii(WvT[(2 * 8 + ks) * 64 + lane], xfr[ks], a2);
    a3 = mfma_ii(WvT[(3 * 8 + ks) * 64 + lane], xfr[ks], a3);
  }

  // softmax: fully lane-local sum over 128 channels, normalize in f32
  float s = 0.f;
  #pragma unroll
  for (int r = 0; r < 16; ++r) {
    a0[r] = __expf(a0[r]); s += a0[r];
    a1[r] = __expf(a1[r]); s += a1[r];
    a2[r] = __expf(a2[r]); s += a2[r];
    a3[r] = __expf(a3[r]); s += a3[r];
  }
  s += __shfl_xor(s, 32);
  const float inv = __builtin_amdgcn_rcpf(s);
  #pragma unroll
  for (int r = 0; r < 16; ++r) {
    a0[r] *= inv; a1[r] *= inv; a2[r] *= inv; a3[r] *= inv;
  }

  // out = v @ Mt^T + bias, two d'-half passes (o-pair live at a time).
  const int4v* MtB = Mtf + ((long)b << 11);
  float* obase = out + row0 * 128 + (l31 << 1);
#define OUT_T2(BASE, T, AT, O0, O1)                                            \
  {                                                                            \
    const int4v f0 = build_frag(AT[0], AT[1], AT[2], AT[3],                    \
                                AT[4], AT[5], AT[6], AT[7], hi);               \
    O0 = mfma_ii(f0, MtB[(BASE) + (2 * T) * 64 + lane], O0);                   \
    O1 = mfma_ii(f0, MtB[(BASE) + 512 + (2 * T) * 64 + lane], O1);             \
    const int4v f1 = build_frag(AT[8], AT[9], AT[10], AT[11],                  \
                                AT[12], AT[13], AT[14], AT[15], hi);           \
    O0 = mfma_ii(f1, MtB[(BASE) + (2 * T + 1) * 64 + lane], O0);               \
    O1 = mfma_ii(f1, MtB[(BASE) + 512 + (2 * T + 1) * 64 + lane], O1);         \
  }
  {  // half A: d' in [0,64)
    f32x16 o0 = {0.f}, o1 = {0.f};
    OUT_T2(0, 0, a0, o0, o1)
    OUT_T2(0, 1, a1, o0, o1)
    OUT_T2(0, 2, a2, o0, o1)
    OUT_T2(0, 3, a3, o0, o1)
    #pragma unroll
    for (int r = 0; r < 16; ++r) {
      const int n = (r & 3) + ((r >> 2) << 3) + (hi << 2);
      f32x2 v;
      v[0] = o0[r] + bA[0];
      v[1] = o1[r] + bA[1];
      *(f32x2*)(obase + (long)n * 128) = v;
    }
  }
  {  // half B: d' in [64,128)
    f32x16 o2 = {0.f}, o3 = {0.f};
    OUT_T2(1024, 0, a0, o2, o3)
    OUT_T2(1024, 1, a1, o2, o3)
    OUT_T2(1024, 2, a2, o2, o3)
    OUT_T2(1024, 3, a3, o2, o3)
    #pragma unroll
    for (int r = 0; r < 16; ++r) {
      const int n = (r & 3) + ((r >> 2) << 3) + (hi << 2);
      f32x2 v;
      v[0] = o2[r] + bB[0];
      v[1] = o3[r] + bB[1];
      *(f32x2*)(obase + 64 + (long)n * 128) = v;
    }
  }
#undef OUT_T2
}

extern "C" void kernel_launch(void* const* d_in, const int* in_sizes, int n_in,
                              void* d_out, int out_size, void* d_ws, size_t ws_size,
                              hipStream_t stream) {
  const float* x = (const float*)d_in[0];
  const float* Wqkv = (const float*)d_in[1];
  const float* Wout = (const float*)d_in[2];
  const float* bout = (const float*)d_in[3];
  float* out = (float*)d_out;

  const int strips = 32;                 // 256 blocks = 1/CU; 16 MB partials

  float* partials = (float*)d_ws;                        // 8*32 * 16384 f32 = 16 MB
  float* ctx = partials + (size_t)8 * strips * 16384;    // 8 * 16384 f32
  int4v* Mtf = (int4v*)(ctx + 8 * 16384);                // 16384 int4v (256 KB)
  int4v* Wf = Mtf + 16384;                               // 6144 int4v (96 KB)

  la_prep<<<dim3(24), dim3(256), 0, stream>>>(Wqkv, Wf);
  la_pass1<<<dim3(8 * strips), dim3(1024), 0, stream>>>(x, Wf, partials);
  la_reduce<<<dim3(128), dim3(256), 0, stream>>>(partials, ctx, strips);
  la_mkern<<<dim3(32), dim3(256), 0, stream>>>(ctx, Wout, Mtf);
  la_pass2<<<dim3(2048), dim3(256), 0, stream>>>(x, Wf, Mtf, bout, out);
}

// Round 19
// 143.860 us; speedup vs baseline: 1.0479x; 1.0010x over previous
//
#include <hip/hip_runtime.h>

#define SEQ 32768
#define QSCALE 0.08838834764831845f
#define NCH 16   // 64-row chunks per strip (strips=32)

typedef __attribute__((ext_vector_type(8))) short short8;
typedef __attribute__((ext_vector_type(8))) __bf16 bf16x8;
typedef __attribute__((ext_vector_type(16))) float f32x16;
typedef __attribute__((ext_vector_type(4))) float f32x4;
typedef __attribute__((ext_vector_type(2))) float f32x2;
typedef __attribute__((ext_vector_type(4))) int int4v;
typedef __attribute__((ext_vector_type(2))) int int2v;

// [R][128]-short tile swizzle: XOR short-idx bits 3..6 with row&15 — all 16
// 16B slots used -> 32-lane b128 column reads are 2-way (free)
#define SWZ(r, c) ((((r) << 7) + (c)) ^ (((r) & 15) << 3))
// [128ch][64n]-short value tile: 8 slots (col space 64 shorts)
#define PSWZ(ch, n) ((((ch) << 6) + (n)) ^ (((ch) & 7) << 3))

__device__ __forceinline__ int cvtpk(float lo, float hi) {
  int r;
  asm("v_cvt_pk_bf16_f32 %0, %1, %2" : "=v"(r) : "v"(lo), "v"(hi));
  return r;
}

__device__ __forceinline__ short bf16b(float f) {
  unsigned u = __builtin_bit_cast(unsigned, f);
  u += 0x7fffu + ((u >> 16) & 1u);   // RNE
  return (short)(u >> 16);
}

__device__ __forceinline__ f32x16 mfma_ii(int4v a, int4v b, f32x16 c) {
  return __builtin_amdgcn_mfma_f32_32x32x16_bf16(
      __builtin_bit_cast(bf16x8, a), __builtin_bit_cast(bf16x8, b), c, 0, 0, 0);
}

// C-layout (reg r <-> n=(r&3)+8*(r>>2)+4*hi, lane) -> A/B frag (reg j <-> n=hi*8+j)
__device__ __forceinline__ int4v build_frag(float e0, float e1, float e2, float e3,
                                            float e4, float e5, float e6, float e7,
                                            int hi) {
  int t0 = cvtpk(e0, e1), t1 = cvtpk(e2, e3);
  int t2 = cvtpk(e4, e5), t3 = cvtpk(e6, e7);
  const int u0 = __shfl_xor(t2, 32), u1 = __shfl_xor(t3, 32);
  const int u2 = __shfl_xor(t0, 32), u3 = __shfl_xor(t1, 32);
  int4v f;
  f[0] = hi ? u0 : t0;
  f[1] = hi ? u1 : t1;
  f[2] = hi ? t2 : u2;
  f[3] = hi ? t3 : u3;
  return f;
}

// ---------------------------------------------------------------------------
// Prep: W fragment table. Wf[side(q,k,v)][tile4][ks8][lane64] = 16B A/B-frag:
// elem j = W[ks*16+(lane>>5)*8+j][side*128 + tile*32 + (lane&31)]  (bf16)
// ---------------------------------------------------------------------------
__global__ void la_prep(const float* __restrict__ Wqkv, int4v* __restrict__ Wf) {
  const int fid = blockIdx.x * 256 + threadIdx.x;  // 6144 frags
  if (fid >= 6144) return;
  const int side = fid >> 11;
  const int rem = fid & 2047;
  const int tile = rem >> 9;
  const int ks = (rem >> 6) & 7;
  const int lane = rem & 63;
  const int k0 = ks * 16 + ((lane >> 5) << 3);
  const int col = side * 128 + tile * 32 + (lane & 31);
  int4v f;
  #pragma unroll
  for (int a = 0; a < 4; ++a)
    f[a] = cvtpk(Wqkv[(k0 + 2 * a) * 384 + col], Wqkv[(k0 + 2 * a + 1) * 384 + col]);
  Wf[fid] = f;
}

// ---------------------------------------------------------------------------
// Pass 1 (r12-exact, proven): single o2 projection, scatter-transpose ptile,
// 1 barrier/chunk, trailing ctx, 16-slot SWZ, q-absorbs-norm.
// grid 256 = 8 batches x 32 strips; 1024 thr (16 waves).
// ---------------------------------------------------------------------------
__global__ __launch_bounds__(1024, 4)
void la_pass1(const float* __restrict__ x, const int4v* __restrict__ Wf,
              float* __restrict__ partials) {
  __shared__ __align__(16) short xs[2][64 * 128];        // 32 KB dbuf
  __shared__ __align__(16) short ptile[2][2][128 * 64];  // 64 KB [buf][side][ch][n]
  __shared__ __align__(16) float sumbuf[2][2][2][32][4]; // 4 KB [buf][side][rh][n][tile]

  const int tid = threadIdx.x;
  const int lane = tid & 63;
  const int wv = tid >> 6;          // 0..15
  const int l31 = lane & 31;
  const int hi = lane >> 5;
  const int koff = hi << 3;
  const int h = wv >> 3;            // 0=q side, 1=k side
  const int c = (wv >> 1) & 3;      // proj ch-tile
  const int rh = wv & 1;            // row half
  const int td = wv >> 2;           // ctx d-tile
  const int te = wv & 3;            // ctx e-tile
  const int b = blockIdx.x >> 5;
  const int strip = blockIdx.x & 31;
  const long base = (long)b * SEQ + (long)strip * (NCH * 64);

  // W fragments for this wave's 32-ch tile (coalesced one-time table load)
  int4v wf[8];
  #pragma unroll
  for (int ks = 0; ks < 8; ++ks)
    wf[ks] = Wf[((((h << 2) + c) << 3) + ks) * 64 + lane];

  const int lr = tid >> 4;          // 0..63
  const int cf = (tid & 15) << 3;   // float col
  {  // preload chunk 0 -> xs[0]
    const float* xp = x + (base + lr) * 128 + cf;
    f32x4 u0 = *(const f32x4*)xp;
    f32x4 u1 = *(const f32x4*)(xp + 4);
    int4v p;
    p[0] = cvtpk(u0[0], u0[1]); p[1] = cvtpk(u0[2], u0[3]);
    p[2] = cvtpk(u1[0], u1[1]); p[3] = cvtpk(u1[2], u1[3]);
    *(int4v*)&xs[0][SWZ(lr, cf)] = p;
  }
  __syncthreads();

  f32x16 ctx = {0.f};
  const int r0 = rh << 5;           // this wave's first row in the chunk
  for (int i = 0; i < NCH; ++i) {
    const int cur = i & 1;
    const int inx = (i + 1 < NCH) ? i + 1 : i;
    const float* xp = x + (base + inx * 64 + lr) * 128 + cf;
    f32x4 u0 = *(const f32x4*)xp;
    f32x4 u1 = *(const f32x4*)(xp + 4);

    // o2: P^T (ch in regs, n in lanes); exp in place -> values AND sums
    f32x16 acc = {0.f};
    #pragma unroll
    for (int ks = 0; ks < 8; ++ks) {
      const int4v xf = *(const int4v*)&xs[cur][SWZ(r0 + l31, (ks << 4) + koff)];
      acc = mfma_ii(wf[ks], xf, acc);
    }
    {
      float sa = 0.f, sb = 0.f;
      #pragma unroll
      for (int r = 0; r < 16; r += 2) {
        acc[r] = __expf(acc[r]);         sa += acc[r];
        acc[r + 1] = __expf(acc[r + 1]); sb += acc[r + 1];
      }
      float s = sa + sb;
      s += __shfl_xor(s, 32);       // lanes n and n+32 hold complementary ch-halves
      if (!hi) sumbuf[cur][h][rh][l31][c] = s;
    }

    {  // stage next chunk (re-write of read buffer is 1 barrier away)
      int4v p;
      p[0] = cvtpk(u0[0], u0[1]); p[1] = cvtpk(u0[2], u0[3]);
      p[2] = cvtpk(u1[0], u1[1]); p[3] = cvtpk(u1[2], u1[3]);
      *(int4v*)&xs[cur ^ 1][SWZ(lr, cf)] = p;
    }
    __syncthreads();                    // the ONLY barrier per chunk

    // trailing ctx on PREVIOUS chunk's tiles FIRST (fills MFMA pipe early)
    if (i > 0) {
      const int pb = cur ^ 1;
      #pragma unroll
      for (int ks = 0; ks < 4; ++ks) {
        const int4v aq = *(const int4v*)&ptile[pb][0][PSWZ((td << 5) + l31, (ks << 4) + koff)];
        const int4v bk = *(const int4v*)&ptile[pb][1][PSWZ((te << 5) + l31, (ks << 4) + koff)];
        ctx = mfma_ii(aq, bk, ctx);
      }
    }

    // norm+transpose write: q absorbs QSCALE/(sq*sk); k stores raw exp
    {
      short* pt = &ptile[cur][h][0];
      const int n = (rh << 5) + l31;
      if (h == 0) {
        const f32x4 sq = *(const f32x4*)&sumbuf[cur][0][rh][l31][0];
        const f32x4 sk = *(const f32x4*)&sumbuf[cur][1][rh][l31][0];
        const float invn = QSCALE * __builtin_amdgcn_rcpf(
            (sq[0] + sq[1] + sq[2] + sq[3]) * (sk[0] + sk[1] + sk[2] + sk[3]));
        #pragma unroll
        for (int r = 0; r < 16; ++r) {
          const int ch = (c << 5) + (r & 3) + ((r >> 2) << 3) + (hi << 2);
          pt[PSWZ(ch, n)] = bf16b(acc[r] * invn);
        }
      } else {
        #pragma unroll
        for (int r = 0; r < 16; ++r) {
          const int ch = (c << 5) + (r & 3) + ((r >> 2) << 3) + (hi << 2);
          pt[PSWZ(ch, n)] = bf16b(acc[r]);
        }
      }
    }
  }
  __syncthreads();   // final: chunk NCH-1 tile writes visible
  {
    const int pb = (NCH - 1) & 1;
    #pragma unroll
    for (int ks = 0; ks < 4; ++ks) {
      const int4v aq = *(const int4v*)&ptile[pb][0][PSWZ((td << 5) + l31, (ks << 4) + koff)];
      const int4v bk = *(const int4v*)&ptile[pb][1][PSWZ((te << 5) + l31, (ks << 4) + koff)];
      ctx = mfma_ii(aq, bk, ctx);
    }
  }

  float* pout = partials + (long)blockIdx.x * 16384;
  #pragma unroll
  for (int r = 0; r < 16; ++r) {
    const int drow = (td << 5) + (r & 3) + ((r >> 2) << 3) + (hi << 2);
    pout[(drow << 7) + (te << 5) + l31] = ctx[r];
  }
}

// ---------------------------------------------------------------------------
// Fused reduce+Mt (r19, fixed): grid 16 = 8 batches x 2 e-halves; 1024 thr.
// Phase 1: reduce this half of ctx[b] from partials straight into LDS.
// Phase 2: 8192 outputs / 1024 thr = 8 e-values per thread (r18 bug: had 16,
// overran the 64-wide half). Each thread writes ONE 16B quarter-frag:
// ks = e0g>>4, sub = (e0g>>3)&1 selects lo/hi lane-half (e = ks*16+sub*8+m).
// ---------------------------------------------------------------------------
__global__ __launch_bounds__(1024, 1)
void la_rm(const float* __restrict__ partials, const float* __restrict__ Wout,
           int4v* __restrict__ Mtf, int strips) {
  __shared__ __align__(16) float cl[128 * 68];   // [d][e-half pad 68], 34.8 KB
  __shared__ __align__(16) float wo[128 * 128];  // full Wout [d][dp], 64 KB

  const int tid = threadIdx.x;
  const int b = blockIdx.x >> 1;
  const int eh = blockIdx.x & 1;
  const int ebase = eh << 6;

  // Phase 1: reduce 8192 f32 (this half) over strips; coalesced 64-f32 rows
  #pragma unroll
  for (int t = 0; t < 2; ++t) {
    const int flat = t * 4096 + tid * 4;          // within the 8192-elem half
    const int d = flat >> 6;
    const int e = flat & 63;
    const long gidx = ((long)d << 7) + ebase + e; // ctx index
    f32x4 acc = {0.f};
    for (int st = 0; st < strips; ++st)
      acc += *(const f32x4*)(partials + (((long)(b * strips + st)) << 14) + gidx);
    *(f32x4*)&cl[d * 68 + e] = acc;
  }
  // Wout -> LDS (full), coalesced
  #pragma unroll
  for (int t = 0; t < 4; ++t) {
    const int i = t * 4096 + tid * 4;
    *(f32x4*)&wo[i] = *(const f32x4*)(Wout + i);
  }
  __syncthreads();

  // Phase 2: each thread computes Mt[dq][e0g..e0g+7]
  const int dq = tid >> 3;                 // d' 0..127
  const int e0 = (tid & 7) << 3;           // e within half: 0..56 step 8
  float acc[8];
  #pragma unroll
  for (int i = 0; i < 8; ++i) acc[i] = 0.f;
  for (int d = 0; d < 128; ++d) {
    const float w = wo[(d << 7) + dq];
    const float* cr = &cl[d * 68 + e0];
    #pragma unroll
    for (int i = 0; i < 8; ++i) acc[i] += cr[i] * w;
  }

  // pair-interleaved Mtf write (r17 layout): d' = half*64 + 2*ll + jj
  const int e0g = ebase + e0;
  const int half = dq >> 6, jj = dq & 1, ll = (dq >> 1) & 31;
  const int ks = e0g >> 4, sub = (e0g >> 3) & 1;
  int4v pk;
  pk[0] = cvtpk(acc[0], acc[1]);
  pk[1] = cvtpk(acc[2], acc[3]);
  pk[2] = cvtpk(acc[4], acc[5]);
  pk[3] = cvtpk(acc[6], acc[7]);
  int4v* dst = Mtf + (long)b * 2048 + half * 1024 + jj * 512 + ks * 64;
  dst[sub * 32 + ll] = pk;
}

// ---------------------------------------------------------------------------
// Pass 2 (r17-exact, proven): barrier-free; two-burst staging; out-GEMM split
// into two d'-half passes; (256,4); pair-interleaved Mtf; coalesced f32x2.
// ---------------------------------------------------------------------------
__global__ __launch_bounds__(256, 4)
void la_pass2(const float* __restrict__ x, const int4v* __restrict__ Wf,
              const int4v* __restrict__ Mtf, const float* __restrict__ bout,
              float* __restrict__ out) {
  __shared__ __align__(16) short xs[4][32 * 128];   // 8 KB per wave

  const int tid = threadIdx.x;
  const int lane = tid & 63;
  const int wv = tid >> 6;
  const int l31 = lane & 31;
  const int hi = lane >> 5;
  const int koff = hi << 3;
  const int b = blockIdx.x >> 8;
  const int chunk = blockIdx.x & 255;
  const long row0 = (long)b * SEQ + (long)chunk * 128 + (wv << 5);

  {  // two-burst stage: 8 loads -> convert+write, 8 loads -> convert+write
    const float* xb = x + row0 * 128;
    f32x4 uA[8];
    #pragma unroll
    for (int t = 0; t < 8; ++t)
      uA[t] = *(const f32x4*)(xb + t * 256 + lane * 4);
    f32x4 uB[8];
    #pragma unroll
    for (int t = 0; t < 8; ++t)
      uB[t] = *(const f32x4*)(xb + (t + 8) * 256 + lane * 4);
    #pragma unroll
    for (int t = 0; t < 8; ++t) {
      const int flat = t * 256 + lane * 4;
      int2v w;
      w[0] = cvtpk(uA[t][0], uA[t][1]);
      w[1] = cvtpk(uA[t][2], uA[t][3]);
      *(int2v*)&xs[wv][SWZ(flat >> 7, flat & 127)] = w;
    }
    #pragma unroll
    for (int t = 0; t < 8; ++t) {
      const int flat = (t + 8) * 256 + lane * 4;
      int2v w;
      w[0] = cvtpk(uB[t][0], uB[t][1]);
      w[1] = cvtpk(uB[t][2], uB[t][3]);
      *(int2v*)&xs[wv][SWZ(flat >> 7, flat & 127)] = w;
    }
  }
  const f32x2 bA = *(const f32x2*)(bout + (l31 << 1));        // d' = 2*l31+j
  const f32x2 bB = *(const f32x2*)(bout + 64 + (l31 << 1));   // d' = 64+2*l31+j
  asm volatile("s_waitcnt lgkmcnt(0)" ::: "memory");          // wave-local LDS drain
  __builtin_amdgcn_sched_barrier(0);

  // x fragments for this wave's 32 rows
  int4v xfr[8];
  #pragma unroll
  for (int ks = 0; ks < 8; ++ks)
    xfr[ks] = *(const int4v*)&xs[wv][SWZ(l31, (ks << 4) + koff)];

  // v-proj o2: C[ch in regs][n=l31], 4 ch-tiles; W-frags from L2 table
  const int4v* WvT = Wf + 2 * 2048;   // side 2 (v)
  f32x16 a0 = {0.f}, a1 = {0.f}, a2 = {0.f}, a3 = {0.f};
  #pragma unroll
  for (int ks = 0; ks < 8; ++ks) {
    a0 = mfma_ii(WvT[(0 * 8 + ks) * 64 + lane], xfr[ks], a0);
    a1 = mfma_ii(WvT[(1 * 8 + ks) * 64 + lane], xfr[ks], a1);
    a2 = mfma_ii(WvT[(2 * 8 + ks) * 64 + lane], xfr[ks], a2);
    a3 = mfma_ii(WvT[(3 * 8 + ks) * 64 + lane], xfr[ks], a3);
  }

  // softmax: fully lane-local sum over 128 channels, normalize in f32
  float s = 0.f;
  #pragma unroll
  for (int r = 0; r < 16; ++r) {
    a0[r] = __expf(a0[r]); s += a0[r];
    a1[r] = __expf(a1[r]); s += a1[r];
    a2[r] = __expf(a2[r]); s += a2[r];
    a3[r] = __expf(a3[r]); s += a3[r];
  }
  s += __shfl_xor(s, 32);
  const float inv = __builtin_amdgcn_rcpf(s);
  #pragma unroll
  for (int r = 0; r < 16; ++r) {
    a0[r] *= inv; a1[r] *= inv; a2[r] *= inv; a3[r] *= inv;
  }

  // out = v @ Mt^T + bias, two d'-half passes (o-pair live at a time).
  const int4v* MtB = Mtf + ((long)b << 11);
  float* obase = out + row0 * 128 + (l31 << 1);
#define OUT_T2(BASE, T, AT, O0, O1)                                            \
  {                                                                            \
    const int4v f0 = build_frag(AT[0], AT[1], AT[2], AT[3],                    \
                                AT[4], AT[5], AT[6], AT[7], hi);               \
    O0 = mfma_ii(f0, MtB[(BASE) + (2 * T) * 64 + lane], O0);                   \
    O1 = mfma_ii(f0, MtB[(BASE) + 512 + (2 * T) * 64 + lane], O1);             \
    const int4v f1 = build_frag(AT[8], AT[9], AT[10], AT[11],                  \
                                AT[12], AT[13], AT[14], AT[15], hi);           \
    O0 = mfma_ii(f1, MtB[(BASE) + (2 * T + 1) * 64 + lane], O0);               \
    O1 = mfma_ii(f1, MtB[(BASE) + 512 + (2 * T + 1) * 64 + lane], O1);         \
  }
  {  // half A: d' in [0,64)
    f32x16 o0 = {0.f}, o1 = {0.f};
    OUT_T2(0, 0, a0, o0, o1)
    OUT_T2(0, 1, a1, o0, o1)
    OUT_T2(0, 2, a2, o0, o1)
    OUT_T2(0, 3, a3, o0, o1)
    #pragma unroll
    for (int r = 0; r < 16; ++r) {
      const int n = (r & 3) + ((r >> 2) << 3) + (hi << 2);
      f32x2 v;
      v[0] = o0[r] + bA[0];
      v[1] = o1[r] + bA[1];
      *(f32x2*)(obase + (long)n * 128) = v;
    }
  }
  {  // half B: d' in [64,128)
    f32x16 o2 = {0.f}, o3 = {0.f};
    OUT_T2(1024, 0, a0, o2, o3)
    OUT_T2(1024, 1, a1, o2, o3)
    OUT_T2(1024, 2, a2, o2, o3)
    OUT_T2(1024, 3, a3, o2, o3)
    #pragma unroll
    for (int r = 0; r < 16; ++r) {
      const int n = (r & 3) + ((r >> 2) << 3) + (hi << 2);
      f32x2 v;
      v[0] = o2[r] + bB[0];
      v[1] = o3[r] + bB[1];
      *(f32x2*)(obase + 64 + (long)n * 128) = v;
    }
  }
#undef OUT_T2
}

extern "C" void kernel_launch(void* const* d_in, const int* in_sizes, int n_in,
                              void* d_out, int out_size, void* d_ws, size_t ws_size,
                              hipStream_t stream) {
  const float* x = (const float*)d_in[0];
  const float* Wqkv = (const float*)d_in[1];
  const float* Wout = (const float*)d_in[2];
  const float* bout = (const float*)d_in[3];
  float* out = (float*)d_out;

  const int strips = 32;                 // 256 blocks = 1/CU; 16 MB partials

  float* partials = (float*)d_ws;                        // 8*32 * 16384 f32 = 16 MB
  int4v* Mtf = (int4v*)(partials + (size_t)8 * strips * 16384);  // 16384 int4v
  int4v* Wf = Mtf + 16384;                               // 6144 int4v (96 KB)

  la_prep<<<dim3(24), dim3(256), 0, stream>>>(Wqkv, Wf);
  la_pass1<<<dim3(8 * strips), dim3(1024), 0, stream>>>(x, Wf, partials);
  la_rm<<<dim3(16), dim3(1024), 0, stream>>>(partials, Wout, Mtf, strips);
  la_pass2<<<dim3(2048), dim3(256), 0, stream>>>(x, Wf, Mtf, bout, out);
}